// Round 4
// baseline (2807.085 us; speedup 1.0000x reference)
//
#include <hip/hip_runtime.h>

typedef unsigned short ushort_t;
typedef __bf16 v8bf __attribute__((ext_vector_type(8)));
typedef float v4f __attribute__((ext_vector_type(4)));

#define B_ 32
#define N_ 1024
#define C_ 768
#define G_ 8
#define HD_ 96
#define CH_ 3072
#define M_ 32768  // B*N

static __device__ __forceinline__ ushort_t f2b(float f) {
    unsigned int u = __float_as_uint(f);
    u += 0x7fff + ((u >> 16) & 1);   // RNE
    return (ushort_t)(u >> 16);
}
static __device__ __forceinline__ unsigned int pk2(float a, float b) {
    return (unsigned int)f2b(a) | ((unsigned int)f2b(b) << 16);
}

// ---------------- depthwise 3x3 conv + residual: out = x + conv(x) ------------
__global__ __launch_bounds__(256) void dwconv_add(
    const float* __restrict__ xin, const float* __restrict__ w,
    const float* __restrict__ bias, float* __restrict__ out)
{
    int p = blockIdx.x;               // b*1024 + h*32 + w
    int b = p >> 10, hw = p & 1023, h = hw >> 5, wq = hw & 31;
    int t = threadIdx.x;
#pragma unroll
    for (int j = 0; j < 3; j++) {
        int c = t + j * 256;
        float acc = bias[c];
#pragma unroll
        for (int dh = 0; dh < 3; dh++) {
            int hh = h + dh - 1;
            if (hh < 0 || hh > 31) continue;
#pragma unroll
            for (int dw = 0; dw < 3; dw++) {
                int ww = wq + dw - 1;
                if (ww < 0 || ww > 31) continue;
                acc += w[c * 9 + dh * 3 + dw] *
                       xin[(size_t)(((b << 10) | (hh << 5) | ww)) * C_ + c];
            }
        }
        size_t o = (size_t)p * C_ + c;
        out[o] = xin[o] + acc;
    }
}

// ---------------- layernorm over C=768 ---------------------------------------
__global__ __launch_bounds__(256) void layernorm_k(
    const float* __restrict__ xin, const float* __restrict__ g,
    const float* __restrict__ bb, float* __restrict__ out)
{
    int row = blockIdx.x;
    int t = threadIdx.x;
    const float* xr = xin + (size_t)row * C_;
    float x0 = xr[t], x1 = xr[t + 256], x2 = xr[t + 512];
    float s1 = x0 + x1 + x2;
    float s2 = x0 * x0 + x1 * x1 + x2 * x2;
#pragma unroll
    for (int o = 32; o > 0; o >>= 1) {
        s1 += __shfl_xor(s1, o);
        s2 += __shfl_xor(s2, o);
    }
    __shared__ float red[8];
    if ((t & 63) == 0) { red[(t >> 6) * 2] = s1; red[(t >> 6) * 2 + 1] = s2; }
    __syncthreads();
    s1 = red[0] + red[2] + red[4] + red[6];
    s2 = red[1] + red[3] + red[5] + red[7];
    float m = s1 * (1.0f / 768.0f);
    float var = s2 * (1.0f / 768.0f) - m * m;
    float inv = rsqrtf(var + 1e-5f);
    float* orow = out + (size_t)row * C_;
    orow[t]       = (x0 - m) * inv * g[t]       + bb[t];
    orow[t + 256] = (x1 - m) * inv * g[t + 256] + bb[t + 256];
    orow[t + 512] = (x2 - m) * inv * g[t + 512] + bb[t + 512];
}

// ---------------- GEMM: out = A @ W^T + bias (+epilogue), fp32 I/O -----------
// A: [M,K] fp32 row-major, W: [Nf,K] fp32 row-major; bf16 MFMA inside.
// EPI: 0 = bias, 1 = bias + exact gelu, 2 = bias + residual (out may alias resid)
template <int EPI>
__global__ __launch_bounds__(256) void gemm_bt(
    const float* __restrict__ A, const float* __restrict__ W,
    const float* __restrict__ bias, const float* __restrict__ resid,
    float* __restrict__ out, int M, int Nf, int K)
{
    __shared__ __align__(16) ushort_t sA[128 * 32];
    __shared__ __align__(16) ushort_t sB[128 * 32];
    int t = threadIdx.x;
    int bm = blockIdx.x;   // M/128
    int bn = blockIdx.y;   // Nf/128
    int wave = t >> 6, lane = t & 63;
    int wm = (wave >> 1) * 64;
    int wn = (wave & 1) * 64;
    int row16 = lane & 15;
    int quad = lane >> 4;
    int sr = t >> 1;            // staging row 0..127
    int sk = (t & 1) * 16;      // staging k offset 0/16

    v4f acc[4][4];
#pragma unroll
    for (int i = 0; i < 4; i++)
#pragma unroll
        for (int j = 0; j < 4; j++) acc[i][j] = (v4f){0.f, 0.f, 0.f, 0.f};

    const float* Arow = A + (size_t)(bm * 128 + sr) * K + sk;
    const float* Wrow = W + (size_t)(bn * 128 + sr) * K + sk;
    uint4* sAdst = (uint4*)(sA + sr * 32 + sk);
    uint4* sBdst = (uint4*)(sB + sr * 32 + sk);

    for (int k0 = 0; k0 < K; k0 += 32) {
        __syncthreads();
        float4 a0 = *(const float4*)(Arow + k0);
        float4 a1 = *(const float4*)(Arow + k0 + 4);
        float4 a2 = *(const float4*)(Arow + k0 + 8);
        float4 a3 = *(const float4*)(Arow + k0 + 12);
        float4 b0 = *(const float4*)(Wrow + k0);
        float4 b1 = *(const float4*)(Wrow + k0 + 4);
        float4 b2 = *(const float4*)(Wrow + k0 + 8);
        float4 b3 = *(const float4*)(Wrow + k0 + 12);
        sAdst[0] = (uint4){pk2(a0.x,a0.y), pk2(a0.z,a0.w), pk2(a1.x,a1.y), pk2(a1.z,a1.w)};
        sAdst[1] = (uint4){pk2(a2.x,a2.y), pk2(a2.z,a2.w), pk2(a3.x,a3.y), pk2(a3.z,a3.w)};
        sBdst[0] = (uint4){pk2(b0.x,b0.y), pk2(b0.z,b0.w), pk2(b1.x,b1.y), pk2(b1.z,b1.w)};
        sBdst[1] = (uint4){pk2(b2.x,b2.y), pk2(b2.z,b2.w), pk2(b3.x,b3.y), pk2(b3.z,b3.w)};
        __syncthreads();
        v8bf af[4], bfr[4];
#pragma unroll
        for (int i = 0; i < 4; i++)
            af[i] = *(const v8bf*)(sA + (wm + i * 16 + row16) * 32 + quad * 8);
#pragma unroll
        for (int j = 0; j < 4; j++)
            bfr[j] = *(const v8bf*)(sB + (wn + j * 16 + row16) * 32 + quad * 8);
#pragma unroll
        for (int i = 0; i < 4; i++)
#pragma unroll
            for (int j = 0; j < 4; j++)
                acc[i][j] = __builtin_amdgcn_mfma_f32_16x16x32_bf16(af[i], bfr[j], acc[i][j], 0, 0, 0);
    }

#pragma unroll
    for (int i = 0; i < 4; i++) {
#pragma unroll
        for (int j = 0; j < 4; j++) {
            int col = bn * 128 + wn + j * 16 + row16;
            float bv = bias[col];
#pragma unroll
            for (int r = 0; r < 4; r++) {
                int row = bm * 128 + wm + i * 16 + quad * 4 + r;
                float v = acc[i][j][r] + bv;
                if (EPI == 1) v = 0.5f * v * (1.0f + erff(v * 0.70710678118f));
                if (EPI == 2) v += resid[(size_t)row * Nf + col];
                out[(size_t)row * Nf + col] = v;
            }
        }
    }
}

// ---------------- channel attention: S = (q^T k)/32, P = softmax(S) ----------
// qkv chunk: [b_local, n, s, g, hd] fp32; one block per (b_local,g); P: [bg,96,96] fp32
__global__ __launch_bounds__(256) void chan_attn(
    const float* __restrict__ qkv, float* __restrict__ P)
{
    __shared__ __align__(16) char smem[49152];
    float* sQ = (float*)smem;                  // [64][96]
    float* sK = (float*)(smem + 24576);        // [64][96]
    float* sS = (float*)smem;                  // [96][97] overlays after compute
    int bg = blockIdx.x;
    int b = bg >> 3, g = bg & 7;
    int t = threadIdx.x;
    int tc = t >> 4, td = t & 15;   // 16x16 thread grid, 6x6 regs each
    float acc[6][6];
#pragma unroll
    for (int i = 0; i < 6; i++)
#pragma unroll
        for (int j = 0; j < 6; j++) acc[i][j] = 0.f;

    for (int n0 = 0; n0 < N_; n0 += 64) {
        __syncthreads();
#pragma unroll
        for (int i = 0; i < 6; i++) {
            int li = t + i * 256;           // 0..1535, float4 units
            int r = li / 24, seg = li % 24;
            size_t qoff = ((size_t)(b * N_ + n0 + r) * 3 + 0) * C_ + g * HD_ + seg * 4;
            *(float4*)(sQ + r * 96 + seg * 4) = *(const float4*)(qkv + qoff);
            *(float4*)(sK + r * 96 + seg * 4) = *(const float4*)(qkv + qoff + C_);
        }
        __syncthreads();
#pragma unroll 4
        for (int n = 0; n < 64; n++) {
            float qv[6], kv[6];
#pragma unroll
            for (int i = 0; i < 6; i++) qv[i] = sQ[n * 96 + tc * 6 + i];
#pragma unroll
            for (int j = 0; j < 6; j++) kv[j] = sK[n * 96 + td * 6 + j];
#pragma unroll
            for (int i = 0; i < 6; i++)
#pragma unroll
                for (int j = 0; j < 6; j++) acc[i][j] += qv[i] * kv[j];
        }
    }
    __syncthreads();
#pragma unroll
    for (int i = 0; i < 6; i++)
#pragma unroll
        for (int j = 0; j < 6; j++)
            sS[(tc * 6 + i) * 97 + td * 6 + j] = acc[i][j] * 0.03125f;
    __syncthreads();
    if (t < 96) {
        float mx = -1e30f;
        for (int d = 0; d < 96; d++) mx = fmaxf(mx, sS[t * 97 + d]);
        float sum = 0.f;
        for (int d = 0; d < 96; d++) sum += __expf(sS[t * 97 + d] - mx);
        float rs = 1.0f / sum;
        float* prow = P + (size_t)bg * 9216 + t * 96;
        for (int d = 0; d < 96; d++) prow[d] = __expf(sS[t * 97 + d] - mx) * rs;
    }
}

// ---------------- attention apply: out[b,n,g,c] = sum_d P[c,d] * v[n,d] ------
__global__ __launch_bounds__(256) void attn_av(
    const float* __restrict__ qkv, const float* __restrict__ P,
    float* __restrict__ out)
{
    __shared__ __align__(16) float sP[96 * 96];  // 36KB
    __shared__ __align__(16) float sV[64 * 96];  // 24KB
    int blk = blockIdx.x;                 // b_local*128 + g*16 + nchunk
    int nch = blk & 15, g = (blk >> 4) & 7, b = blk >> 7;
    int t = threadIdx.x;
#pragma unroll
    for (int i = 0; i < 9; i++) {
        int li = t + i * 256;              // float4 units, 2304 total
        if (li < 2304)
            *(float4*)(sP + li * 4) = *(const float4*)(P + (size_t)(b * 8 + g) * 9216 + li * 4);
    }
    int n0 = nch * 64;
#pragma unroll
    for (int i = 0; i < 6; i++) {
        int li = t + i * 256;              // 0..1535 float4 units
        int r = li / 24, seg = li % 24;
        size_t voff = ((size_t)(b * N_ + n0 + r) * 3 + 2) * C_ + g * HD_ + seg * 4;
        *(float4*)(sV + r * 96 + seg * 4) = *(const float4*)(qkv + voff);
    }
    __syncthreads();
    int tn = t >> 4, tc = t & 15;   // 4 n's, 6 c's per thread
    float acc[4][6];
#pragma unroll
    for (int i = 0; i < 4; i++)
#pragma unroll
        for (int j = 0; j < 6; j++) acc[i][j] = 0.f;
#pragma unroll 4
    for (int d = 0; d < 96; d++) {
        float vv[4], pv[6];
#pragma unroll
        for (int i = 0; i < 4; i++) vv[i] = sV[(tn * 4 + i) * 96 + d];
#pragma unroll
        for (int j = 0; j < 6; j++) pv[j] = sP[(tc * 6 + j) * 96 + d];
#pragma unroll
        for (int i = 0; i < 4; i++)
#pragma unroll
            for (int j = 0; j < 6; j++) acc[i][j] += vv[i] * pv[j];
    }
#pragma unroll
    for (int i = 0; i < 4; i++) {
        int n = n0 + tn * 4 + i;
        size_t base = ((size_t)(b * N_ + n)) * C_ + g * HD_ + tc * 6;
#pragma unroll
        for (int j = 0; j < 6; j++) out[base + j] = acc[i][j];
    }
}

// -----------------------------------------------------------------------------
// Adaptive chunked pipeline, fp32 everywhere. Per chunk of CB batches
// (R = CB*1024 rows): ln1(x1)->L ; qkv: L->D ; attn: D->P ; av: D,P->A ;
// proj: A (+x1)->X2 ; dw2: X2->x3 (d_out) ; ln2->L ; fc1+gelu: L->D ;
// fc2: D (+x3)->d_out (alias-safe). ws = CB * 22,315,008 B.
extern "C" void kernel_launch(void* const* d_in, const int* in_sizes, int n_in,
                              void* d_out, int out_size, void* d_ws, size_t ws_size,
                              hipStream_t stream)
{
    const float* x      = (const float*)d_in[0];
    const float* dw1_w  = (const float*)d_in[3];
    const float* dw1_b  = (const float*)d_in[4];
    const float* ln1_g  = (const float*)d_in[5];
    const float* ln1_b  = (const float*)d_in[6];
    const float* qkv_w  = (const float*)d_in[7];
    const float* qkv_b  = (const float*)d_in[8];
    const float* proj_w = (const float*)d_in[9];
    const float* proj_b = (const float*)d_in[10];
    const float* dw2_w  = (const float*)d_in[11];
    const float* dw2_b  = (const float*)d_in[12];
    const float* ln2_g  = (const float*)d_in[13];
    const float* ln2_b  = (const float*)d_in[14];
    const float* fc1_w  = (const float*)d_in[15];
    const float* fc1_b  = (const float*)d_in[16];
    const float* fc2_w  = (const float*)d_in[17];
    const float* fc2_b  = (const float*)d_in[18];
    float* outp = (float*)d_out;    // holds x1, then x3, then final out

    // pick chunk size (batches) to fit workspace
    size_t CB = 32;
    while (CB > 1 && CB * 22315008ull > ws_size) CB >>= 1;
    const size_t R = CB * 1024;                 // rows per chunk
    char* ws = (char*)d_ws;
    float* L  = (float*)ws;                                    // [R,768]
    float* Ab = (float*)(ws + R * C_ * 4);                     // [R,768]
    float* X2 = (float*)(ws + 2 * R * C_ * 4);                 // [R,768]
    float* P  = (float*)(ws + 3 * R * C_ * 4);                 // [CB*8,96,96]
    float* D  = (float*)(ws + 3 * R * C_ * 4 + CB * 294912);   // [R,3072]

    // 1. x1 = x + dwconv1(x) -> d_out  (full)
    dwconv_add<<<M_, 256, 0, stream>>>(x, dw1_w, dw1_b, outp);

    const int nchunk = (int)(32 / CB);
    for (int c = 0; c < nchunk; c++) {
        float* xc = outp + (size_t)c * R * C_;   // x1 chunk, later x3 chunk
        layernorm_k<<<(int)R, 256, 0, stream>>>(xc, ln1_g, ln1_b, L);
        gemm_bt<0><<<dim3((int)R / 128, 2304 / 128), 256, 0, stream>>>(
            L, qkv_w, qkv_b, nullptr, D, (int)R, 2304, C_);
        chan_attn<<<(int)CB * 8, 256, 0, stream>>>(D, P);
        attn_av<<<(int)CB * 128, 256, 0, stream>>>(D, P, Ab);
        gemm_bt<2><<<dim3((int)R / 128, C_ / 128), 256, 0, stream>>>(
            Ab, proj_w, proj_b, xc, X2, (int)R, C_, C_);
        dwconv_add<<<(int)R, 256, 0, stream>>>(X2, dw2_w, dw2_b, xc);
        layernorm_k<<<(int)R, 256, 0, stream>>>(xc, ln2_g, ln2_b, L);
        gemm_bt<1><<<dim3((int)R / 128, CH_ / 128), 256, 0, stream>>>(
            L, fc1_w, fc1_b, nullptr, D, (int)R, CH_, C_);
        gemm_bt<2><<<dim3((int)R / 128, C_ / 128), 256, 0, stream>>>(
            D, fc2_w, fc2_b, xc, xc, (int)R, C_, CH_);
    }
}

// Round 5
// 2114.054 us; speedup vs baseline: 1.3278x; 1.3278x over previous
//
#include <hip/hip_runtime.h>

typedef unsigned short ushort_t;
typedef __bf16 v8bf __attribute__((ext_vector_type(8)));
typedef float v4f __attribute__((ext_vector_type(4)));

#define B_ 32
#define N_ 1024
#define C_ 768
#define G_ 8
#define HD_ 96
#define CH_ 3072
#define M_ 32768  // B*N

static __device__ __forceinline__ float b2f(ushort_t u) {
    union { float f; unsigned int i; } z; z.i = ((unsigned int)u) << 16; return z.f;
}
static __device__ __forceinline__ ushort_t f2b(float f) {
    unsigned int u = __float_as_uint(f);
    u += 0x7fff + ((u >> 16) & 1);   // RNE
    return (ushort_t)(u >> 16);
}
static __device__ __forceinline__ unsigned int pk2(float a, float b) {
    return (unsigned int)f2b(a) | ((unsigned int)f2b(b) << 16);
}

#define GLOAD_LDS16(g, l) __builtin_amdgcn_global_load_lds( \
    (const __attribute__((address_space(1))) unsigned int*)(g), \
    (__attribute__((address_space(3))) unsigned int*)(l), 16, 0, 0)

// ---------------- fp32 -> bf16 weight conversion (4 elems/thread) -------------
__global__ __launch_bounds__(256) void cvt_bf16(
    const float* __restrict__ in, ushort_t* __restrict__ out)
{
    int i = (blockIdx.x * 256 + threadIdx.x) * 4;
    float4 v = *(const float4*)(in + i);
    uint2 p; p.x = pk2(v.x, v.y); p.y = pk2(v.z, v.w);
    *(uint2*)(out + i) = p;
}

// ---------------- depthwise 3x3 conv + residual (fp32): out = x + conv(x) ----
__global__ __launch_bounds__(256) void dwconv_add(
    const float* __restrict__ xin, const float* __restrict__ w,
    const float* __restrict__ bias, float* __restrict__ out)
{
    int p = blockIdx.x;               // b*1024 + h*32 + w
    int b = p >> 10, hw = p & 1023, h = hw >> 5, wq = hw & 31;
    int t = threadIdx.x;
#pragma unroll
    for (int j = 0; j < 3; j++) {
        int c = t + j * 256;
        float acc = bias[c];
#pragma unroll
        for (int dh = 0; dh < 3; dh++) {
            int hh = h + dh - 1;
            if (hh < 0 || hh > 31) continue;
#pragma unroll
            for (int dw = 0; dw < 3; dw++) {
                int ww = wq + dw - 1;
                if (ww < 0 || ww > 31) continue;
                acc += w[c * 9 + dh * 3 + dw] *
                       xin[(size_t)(((b << 10) | (hh << 5) | ww)) * C_ + c];
            }
        }
        size_t o = (size_t)p * C_ + c;
        out[o] = xin[o] + acc;
    }
}

// ---------------- layernorm over C=768: fp32 in -> bf16 out -------------------
__global__ __launch_bounds__(256) void layernorm_bf(
    const float* __restrict__ xin, const float* __restrict__ g,
    const float* __restrict__ bb, ushort_t* __restrict__ out)
{
    int row = blockIdx.x;
    int t = threadIdx.x;
    const float* xr = xin + (size_t)row * C_;
    float x0 = xr[t], x1 = xr[t + 256], x2 = xr[t + 512];
    float s1 = x0 + x1 + x2;
    float s2 = x0 * x0 + x1 * x1 + x2 * x2;
#pragma unroll
    for (int o = 32; o > 0; o >>= 1) {
        s1 += __shfl_xor(s1, o);
        s2 += __shfl_xor(s2, o);
    }
    __shared__ float red[8];
    if ((t & 63) == 0) { red[(t >> 6) * 2] = s1; red[(t >> 6) * 2 + 1] = s2; }
    __syncthreads();
    s1 = red[0] + red[2] + red[4] + red[6];
    s2 = red[1] + red[3] + red[5] + red[7];
    float m = s1 * (1.0f / 768.0f);
    float var = s2 * (1.0f / 768.0f) - m * m;
    float inv = rsqrtf(var + 1e-5f);
    ushort_t* orow = out + (size_t)row * C_;
    orow[t]       = f2b((x0 - m) * inv * g[t]       + bb[t]);
    orow[t + 256] = f2b((x1 - m) * inv * g[t + 256] + bb[t + 256]);
    orow[t + 512] = f2b((x2 - m) * inv * g[t + 512] + bb[t + 512]);
}

// ---------------- bf16 GEMM (m97-style, global_load_lds staging) --------------
// A: [M,K] bf16 row-major, W: [Nf,K] bf16 row-major => out = A @ W^T + bias
// EPI 0: bf16 out = acc+bias ; EPI 1: bf16 out = gelu(acc+bias) ;
// EPI 2: fp32 out = acc+bias+resid(fp32)  (out may alias resid)
template <int EPI>
__global__ __launch_bounds__(256) void gemm_bt(
    const ushort_t* __restrict__ A, const ushort_t* __restrict__ W,
    const float* __restrict__ bias, const float* __restrict__ resid,
    void* __restrict__ outv, int M, int Nf, int K)
{
    __shared__ __align__(16) ushort_t sA[128 * 32];
    __shared__ __align__(16) ushort_t sB[128 * 32];
    int t = threadIdx.x;
    int bm = blockIdx.x;   // M/128
    int bn = blockIdx.y;   // Nf/128
    int wave = t >> 6, lane = t & 63;
    int wm = (wave >> 1) * 64;
    int wn = (wave & 1) * 64;
    int row16 = lane & 15;
    int quad = lane >> 4;

    // global_load_lds staging: issue r in {0,1}; wave w stages LDS rows
    // [(w+4r)*16, +16). Lane i -> row (w+4r)*16 + i/4, 16B-seg i%4.
    // LDS linear offset = wave-uniform base + i*16  (HW contract).
    int r0 = wave * 16 + (lane >> 2);
    int r1 = (wave + 4) * 16 + (lane >> 2);
    int c8 = (lane & 3) * 8;              // element offset of 16B segment
    const ushort_t* Ag0 = A + (size_t)(bm * 128 + r0) * K + c8;
    const ushort_t* Ag1 = A + (size_t)(bm * 128 + r1) * K + c8;
    const ushort_t* Wg0 = W + (size_t)(bn * 128 + r0) * K + c8;
    const ushort_t* Wg1 = W + (size_t)(bn * 128 + r1) * K + c8;
    ushort_t* sA0 = sA + wave * 512;      // (w+4r)*1024 bytes
    ushort_t* sA1 = sA + (wave + 4) * 512;
    ushort_t* sB0 = sB + wave * 512;
    ushort_t* sB1 = sB + (wave + 4) * 512;

    v4f acc[4][4];
#pragma unroll
    for (int i = 0; i < 4; i++)
#pragma unroll
        for (int j = 0; j < 4; j++) acc[i][j] = (v4f){0.f, 0.f, 0.f, 0.f};

    for (int k0 = 0; k0 < K; k0 += 32) {
        __syncthreads();                       // LDS free (prev MFMA reads done)
        GLOAD_LDS16(Ag0 + k0, sA0);
        GLOAD_LDS16(Ag1 + k0, sA1);
        GLOAD_LDS16(Wg0 + k0, sB0);
        GLOAD_LDS16(Wg1 + k0, sB1);
        __syncthreads();                       // drains vmcnt -> staging visible
        v8bf af[4], bfr[4];
#pragma unroll
        for (int i = 0; i < 4; i++)
            af[i] = *(const v8bf*)(sA + (wm + i * 16 + row16) * 32 + quad * 8);
#pragma unroll
        for (int j = 0; j < 4; j++)
            bfr[j] = *(const v8bf*)(sB + (wn + j * 16 + row16) * 32 + quad * 8);
#pragma unroll
        for (int i = 0; i < 4; i++)
#pragma unroll
            for (int j = 0; j < 4; j++)
                acc[i][j] = __builtin_amdgcn_mfma_f32_16x16x32_bf16(af[i], bfr[j], acc[i][j], 0, 0, 0);
    }

#pragma unroll
    for (int i = 0; i < 4; i++) {
#pragma unroll
        for (int j = 0; j < 4; j++) {
            int col = bn * 128 + wn + j * 16 + row16;
            float bv = bias[col];
#pragma unroll
            for (int r = 0; r < 4; r++) {
                int row = bm * 128 + wm + i * 16 + quad * 4 + r;
                float v = acc[i][j][r] + bv;
                if (EPI == 1) v = 0.5f * v * (1.0f + erff(v * 0.70710678118f));
                if (EPI == 2) {
                    v += resid[(size_t)row * Nf + col];
                    ((float*)outv)[(size_t)row * Nf + col] = v;
                } else {
                    ((ushort_t*)outv)[(size_t)row * Nf + col] = f2b(v);
                }
            }
        }
    }
}

// ---------------- channel attention: S = (q^T k)/32, P = softmax(S) ----------
// qkv chunk: [b_local, n, s, g, hd] bf16; one block per (b_local,g); P bf16
__global__ __launch_bounds__(256) void chan_attn(
    const ushort_t* __restrict__ qkv, ushort_t* __restrict__ P)
{
    __shared__ __align__(16) char smem[96 * 97 * 4];
    ushort_t* sQ = (ushort_t*)smem;                 // [64][96] bf16
    ushort_t* sK = (ushort_t*)(smem + 64 * 96 * 2); // [64][96] bf16
    float* sS = (float*)smem;                       // [96][97] fp32 (after)
    int bg = blockIdx.x;
    int b = bg >> 3, g = bg & 7;
    int t = threadIdx.x;
    int tc = t >> 4, td = t & 15;   // 16x16 thread grid, 6x6 regs each
    float acc[6][6];
#pragma unroll
    for (int i = 0; i < 6; i++)
#pragma unroll
        for (int j = 0; j < 6; j++) acc[i][j] = 0.f;

    for (int n0 = 0; n0 < N_; n0 += 64) {
        __syncthreads();
#pragma unroll
        for (int i = 0; i < 3; i++) {
            int li = t + i * 256;           // 0..767, uint4 units (8 bf16)
            int r = li / 12, seg = li % 12;
            size_t qoff = ((size_t)(b * N_ + n0 + r) * 3 + 0) * C_ + g * HD_ + seg * 8;
            *(uint4*)(sQ + r * 96 + seg * 8) = *(const uint4*)(qkv + qoff);
            *(uint4*)(sK + r * 96 + seg * 8) = *(const uint4*)(qkv + qoff + C_);
        }
        __syncthreads();
#pragma unroll 4
        for (int n = 0; n < 64; n++) {
            float qv[6], kv[6];
#pragma unroll
            for (int i = 0; i < 6; i++) qv[i] = b2f(sQ[n * 96 + tc * 6 + i]);
#pragma unroll
            for (int j = 0; j < 6; j++) kv[j] = b2f(sK[n * 96 + td * 6 + j]);
#pragma unroll
            for (int i = 0; i < 6; i++)
#pragma unroll
                for (int j = 0; j < 6; j++) acc[i][j] += qv[i] * kv[j];
        }
    }
    __syncthreads();
#pragma unroll
    for (int i = 0; i < 6; i++)
#pragma unroll
        for (int j = 0; j < 6; j++)
            sS[(tc * 6 + i) * 97 + td * 6 + j] = acc[i][j] * 0.03125f;
    __syncthreads();
    if (t < 96) {
        float mx = -1e30f;
        for (int d = 0; d < 96; d++) mx = fmaxf(mx, sS[t * 97 + d]);
        float sum = 0.f;
        for (int d = 0; d < 96; d++) sum += __expf(sS[t * 97 + d] - mx);
        float rs = 1.0f / sum;
        ushort_t* prow = P + (size_t)bg * 9216 + t * 96;
        for (int d = 0; d < 96; d++) prow[d] = f2b(__expf(sS[t * 97 + d] - mx) * rs);
    }
}

// ---------------- attention apply: out[b,n,g,c] = sum_d P[c,d] * v[n,d] ------
__global__ __launch_bounds__(256) void attn_av(
    const ushort_t* __restrict__ qkv, const ushort_t* __restrict__ P,
    ushort_t* __restrict__ out)
{
    __shared__ __align__(16) ushort_t sP[96 * 96];  // 18KB bf16
    __shared__ __align__(16) ushort_t sV[64 * 96];  // 12KB bf16
    int blk = blockIdx.x;                 // b_local*128 + g*16 + nchunk
    int nch = blk & 15, g = (blk >> 4) & 7, b = blk >> 7;
    int t = threadIdx.x;
#pragma unroll
    for (int i = 0; i < 5; i++) {
        int li = t + i * 256;
        if (li < 1152)
            *(uint4*)(sP + li * 8) = *(const uint4*)(P + (size_t)(b * 8 + g) * 9216 + li * 8);
    }
    int n0 = nch * 64;
#pragma unroll
    for (int i = 0; i < 3; i++) {
        int li = t + i * 256;
        int r = li / 12, seg = li % 12;
        size_t voff = ((size_t)(b * N_ + n0 + r) * 3 + 2) * C_ + g * HD_ + seg * 8;
        *(uint4*)(sV + r * 96 + seg * 8) = *(const uint4*)(qkv + voff);
    }
    __syncthreads();
    int tn = t >> 4, tc = t & 15;   // 4 n's, 6 c's per thread
    float acc[4][6];
#pragma unroll
    for (int i = 0; i < 4; i++)
#pragma unroll
        for (int j = 0; j < 6; j++) acc[i][j] = 0.f;
#pragma unroll 4
    for (int d = 0; d < 96; d++) {
        float vv[4], pv[6];
#pragma unroll
        for (int i = 0; i < 4; i++) vv[i] = b2f(sV[(tn * 4 + i) * 96 + d]);
#pragma unroll
        for (int j = 0; j < 6; j++) pv[j] = b2f(sP[(tc * 6 + j) * 96 + d]);
#pragma unroll
        for (int i = 0; i < 4; i++)
#pragma unroll
            for (int j = 0; j < 6; j++) acc[i][j] += vv[i] * pv[j];
    }
#pragma unroll
    for (int i = 0; i < 4; i++) {
        int n = n0 + tn * 4 + i;
        size_t base = ((size_t)(b * N_ + n)) * C_ + g * HD_ + tc * 6;
#pragma unroll
        for (int j = 0; j < 6; j++) out[base + j] = f2b(acc[i][j]);
    }
}

// -----------------------------------------------------------------------------
// bf16-internal chunked pipeline. Residual chain (x1/x2/x3/out) fp32.
// ws layout: [bf16 weights 14.16 MB][L bf16][A bf16][X2 fp32][P bf16][D bf16]
// per-batch cost 12,730,368 B; CB adaptive.
extern "C" void kernel_launch(void* const* d_in, const int* in_sizes, int n_in,
                              void* d_out, int out_size, void* d_ws, size_t ws_size,
                              hipStream_t stream)
{
    const float* x      = (const float*)d_in[0];
    const float* dw1_w  = (const float*)d_in[3];
    const float* dw1_b  = (const float*)d_in[4];
    const float* ln1_g  = (const float*)d_in[5];
    const float* ln1_b  = (const float*)d_in[6];
    const float* qkv_w  = (const float*)d_in[7];
    const float* qkv_b  = (const float*)d_in[8];
    const float* proj_w = (const float*)d_in[9];
    const float* proj_b = (const float*)d_in[10];
    const float* dw2_w  = (const float*)d_in[11];
    const float* dw2_b  = (const float*)d_in[12];
    const float* ln2_g  = (const float*)d_in[13];
    const float* ln2_b  = (const float*)d_in[14];
    const float* fc1_w  = (const float*)d_in[15];
    const float* fc1_b  = (const float*)d_in[16];
    const float* fc2_w  = (const float*)d_in[17];
    const float* fc2_b  = (const float*)d_in[18];
    float* outp = (float*)d_out;    // holds x1, then x3, then final out

    char* ws = (char*)d_ws;
    // bf16 weight arena
    ushort_t* qkvW = (ushort_t*)ws;                          // 2304*768
    ushort_t* projW = qkvW + 2304 * 768;                     // 768*768
    ushort_t* fc1W = projW + 768 * 768;                      // 3072*768
    ushort_t* fc2W = fc1W + 3072 * 768;                      // 768*3072
    const size_t WB = (size_t)(2304*768 + 768*768 + 3072*768 + 768*3072) * 2; // 14,155,776

    size_t CB = 32;
    while (CB > 1 && WB + CB * 12730368ull > ws_size) CB >>= 1;
    const size_t R = CB * 1024;
    char* act = ws + WB;
    ushort_t* L  = (ushort_t*)act;                           // [R,768] bf16
    ushort_t* Ab = (ushort_t*)(act + R * C_ * 2);            // [R,768] bf16
    float*    X2 = (float*)(act + 2 * R * C_ * 2);           // [R,768] fp32
    ushort_t* P  = (ushort_t*)(act + 2 * R * C_ * 2 + R * C_ * 4);
    ushort_t* D  = (ushort_t*)(act + 2 * R * C_ * 2 + R * C_ * 4 + CB * 147456);

    // 0. weight conversion fp32 -> bf16
    cvt_bf16<<<2304 * 768 / 1024, 256, 0, stream>>>(qkv_w, qkvW);
    cvt_bf16<<<768 * 768 / 1024, 256, 0, stream>>>(proj_w, projW);
    cvt_bf16<<<3072 * 768 / 1024, 256, 0, stream>>>(fc1_w, fc1W);
    cvt_bf16<<<768 * 3072 / 1024, 256, 0, stream>>>(fc2_w, fc2W);

    // 1. x1 = x + dwconv1(x) -> d_out  (full, fp32)
    dwconv_add<<<M_, 256, 0, stream>>>(x, dw1_w, dw1_b, outp);

    const int nchunk = (int)(32 / CB);
    for (int c = 0; c < nchunk; c++) {
        float* xc = outp + (size_t)c * R * C_;   // x1 chunk, later x3 chunk
        // ln1 -> L (bf16)
        layernorm_bf<<<(int)R, 256, 0, stream>>>(xc, ln1_g, ln1_b, L);
        // qkv = L @ qkvW^T + b -> D (bf16)
        gemm_bt<0><<<dim3((int)R / 128, 2304 / 128), 256, 0, stream>>>(
            L, qkvW, qkv_b, nullptr, D, (int)R, 2304, C_);
        // P = softmax(q^T k / 32)
        chan_attn<<<(int)CB * 8, 256, 0, stream>>>(D, P);
        // A = P @ v (bf16)
        attn_av<<<(int)CB * 128, 256, 0, stream>>>(D, P, Ab);
        // x2 = x1 + A @ projW^T + b -> X2 (fp32)
        gemm_bt<2><<<dim3((int)R / 128, C_ / 128), 256, 0, stream>>>(
            Ab, projW, proj_b, xc, X2, (int)R, C_, C_);
        // x3 = x2 + dwconv2(x2) -> d_out chunk (fp32)
        dwconv_add<<<(int)R, 256, 0, stream>>>(X2, dw2_w, dw2_b, xc);
        // ln2 -> L (bf16)
        layernorm_bf<<<(int)R, 256, 0, stream>>>(xc, ln2_g, ln2_b, L);
        // h = gelu(L @ fc1W^T + b) -> D (bf16)
        gemm_bt<1><<<dim3((int)R / 128, CH_ / 128), 256, 0, stream>>>(
            L, fc1W, fc1_b, nullptr, D, (int)R, CH_, C_);
        // out = x3 + h @ fc2W^T + b -> d_out chunk (fp32, alias-safe)
        gemm_bt<2><<<dim3((int)R / 128, C_ / 128), 256, 0, stream>>>(
            D, fc2W, fc2_b, xc, xc, (int)R, C_, CH_);
    }
}